// Round 14
// baseline (420.761 us; speedup 1.0000x reference)
//
#include <hip/hip_runtime.h>
#include <hip/hip_cooperative_groups.h>
#include <stdint.h>

namespace cg = cooperative_groups;

#define BATCH 128
#define LCOUNT 196
#define LP1 197
#define DIM 1024

typedef __bf16 bf16x8 __attribute__((ext_vector_type(8)));
typedef float f32x4 __attribute__((ext_vector_type(4)));

__device__ inline float bf2f(uint16_t h){ union{uint32_t i; float f;} x; x.i = ((uint32_t)h) << 16; return x.f; }
__device__ inline uint32_t f2bf(float f){
  union{float f; uint32_t u;} x; x.f = f;
  uint32_t r = x.u + 0x7fffu + ((x.u >> 16) & 1u);
  return r >> 16;
}
__device__ inline float tanh_fast(float x){
  float e = __expf(2.0f * x);
  return 1.0f - 2.0f / (e + 1.0f);
}

// load 8 contiguous fp32 and convert to bf16x8 (RNE, same as f2bf)
__device__ inline bf16x8 cvt8(const float* p){
  float4 a = *(const float4*)p;
  float4 b = *(const float4*)(p + 4);
  bf16x8 r;
  r[0] = (__bf16)a.x; r[1] = (__bf16)a.y; r[2] = (__bf16)a.z; r[3] = (__bf16)a.w;
  r[4] = (__bf16)b.x; r[5] = (__bf16)b.y; r[6] = (__bf16)b.z; r[7] = (__bf16)b.w;
  return r;
}

// ---- 16x16 GEMM tile, 512 threads, 8-way split-K (R12-measured body) -------
// C[m,n] = act(sum_k A[m,k]*W[n,k] + bias[n]); C/D layout col=lane&15,
// row=quad*4+i (verified m89/m91; R4/R12 pass).
template<int AF32, int WF32>
__device__ void gemm_tile512(const void* A, const void* W, const float* bias,
                             uint16_t* out_bf, float* out_f, int act,
                             int m0, int n0, float (*lds)[256]) {
  const int K = DIM, N = DIM;
  int wave = threadIdx.x >> 6;          // 0..7, K-slice index
  int lane = threadIdx.x & 63;
  int r    = lane & 15;
  int quad = lane >> 4;
  size_t aoff = (size_t)(m0 + r) * K + wave * 128 + quad * 8;
  size_t woff = (size_t)(n0 + r) * K + wave * 128 + quad * 8;
  const float*    Af = (const float*)A    + aoff;
  const uint16_t* Ab = (const uint16_t*)A + aoff;
  const float*    Wf = (const float*)W    + woff;
  const uint16_t* Wb = (const uint16_t*)W + woff;
  f32x4 acc = {0.f, 0.f, 0.f, 0.f};
  #pragma unroll
  for (int k = 0; k < 128; k += 32) {
    bf16x8 a = AF32 ? cvt8(Af + k) : *(const bf16x8*)(Ab + k);
    bf16x8 b = WF32 ? cvt8(Wf + k) : *(const bf16x8*)(Wb + k);
    acc = __builtin_amdgcn_mfma_f32_16x16x32_bf16(a, b, acc, 0, 0, 0);
  }
  __syncthreads();                       // LDS reuse guard (prev use)
  int li = lane * 4;
  lds[wave][li+0] = acc[0]; lds[wave][li+1] = acc[1];
  lds[wave][li+2] = acc[2]; lds[wave][li+3] = acc[3];
  __syncthreads();
  int t = threadIdx.x;
  if (t < 256) {
    float v = lds[0][t] + lds[1][t] + lds[2][t] + lds[3][t]
            + lds[4][t] + lds[5][t] + lds[6][t] + lds[7][t];
    int col = (t >> 2) & 15;             // lane&15 of producer
    int row = (t >> 6) * 4 + (t & 3);    // quad*4 + i of producer
    v += bias[n0 + col];
    if (act == 1) v = fmaxf(v, 0.f);
    else if (act == 2) v = tanh_fast(v);
    size_t idx = (size_t)(m0 + row) * N + (n0 + col);
    if (out_bf) out_bf[idx] = (uint16_t)f2bf(v);
    if (out_f)  out_f[idx]  = v;
  }
}

struct FusedArgs {
  const float *h_out, *fake_region, *conv_feat, *conv_feat_e;
  const float *W_fr, *b_fr, *W_fre, *b_fre;
  const float *W_ho, *b_ho, *W_hoe, *b_hoe;
  const float *W_a, *b_a, *W_h, *b_h;
  uint16_t *fr_bf, *ho_bf, *attout;
  float *ho_f, *fre_f, *hoe_f, *scores, *out;
};

// ==== K12: steps 1+2 (4 GEMMs) in one coop kernel, 2 grid phases =============
// 1024 tile-jobs per phase over up-to-1024 blocks (full TLP: 16+ waves/CU).
__global__ __launch_bounds__(512, 2) void k12(FusedArgs a) {
  cg::grid_group grid = cg::this_grid();
  __shared__ float lds[8][256];
  const int nb = gridDim.x, bid = blockIdx.x;
  // phase 1: fr = relu(freg@W_fr^T+b), ho = tanh(h_out@W_ho^T+b)
  for (int j = bid; j < 1024; j += nb) {
    int tl = j & 511;
    int m0 = (tl & 7) * 16, n0 = (tl >> 3) * 16;
    if (j < 512)
      gemm_tile512<1,1>(a.fake_region, a.W_fr, a.b_fr, a.fr_bf, nullptr, 1, m0, n0, lds);
    else
      gemm_tile512<1,1>(a.h_out, a.W_ho, a.b_ho, a.ho_bf, a.ho_f, 2, m0, n0, lds);
  }
  grid.sync();
  // phase 2: fr_e = fr@W_fre^T+b, ho_e = ho@W_hoe^T+b
  for (int j = bid; j < 1024; j += nb) {
    int tl = j & 511;
    int m0 = (tl & 7) * 16, n0 = (tl >> 3) * 16;
    if (j < 512)
      gemm_tile512<0,1>(a.fr_bf, a.W_fre, a.b_fre, nullptr, a.fre_f, 0, m0, n0, lds);
    else
      gemm_tile512<0,1>(a.ho_bf, a.W_hoe, a.b_hoe, nullptr, a.hoe_f, 0, m0, n0, lds);
  }
}

// ==== K45: visatt + step-5 GEMM in one coop kernel, 2 grid phases ============
union Sm45 {
  float glds[8][256];
  struct { float pis[LP1]; float red[8]; float partial[8][256]; } v;
};

__global__ __launch_bounds__(512, 2) void k45(FusedArgs a) {
  cg::grid_group grid = cg::this_grid();
  __shared__ Sm45 sm;
  const int nb = gridDim.x, bid = blockIdx.x;
  int t = threadIdx.x, lane = t & 63, wave = t >> 6;

  // phase 1: softmax + visAtt + ho -> attout. 512 jobs (b, chunk).
  for (int job = bid; job < BATCH * 4; job += nb) {
    int b = job >> 2, cy = job & 3;
    __syncthreads();                     // LDS reuse guard across iters
    float v = (t < LP1) ? a.scores[b * LP1 + t] : -1e30f;
    float m = v;
    #pragma unroll
    for (int off = 32; off > 0; off >>= 1) m = fmaxf(m, __shfl_down(m, off));
    if (lane == 0) sm.v.red[wave] = m;
    __syncthreads();
    m = fmaxf(fmaxf(fmaxf(sm.v.red[0], sm.v.red[1]), fmaxf(sm.v.red[2], sm.v.red[3])),
              fmaxf(fmaxf(sm.v.red[4], sm.v.red[5]), fmaxf(sm.v.red[6], sm.v.red[7])));
    float e = (t < LP1) ? __expf(v - m) : 0.f;
    float s = e;
    #pragma unroll
    for (int off = 32; off > 0; off >>= 1) s += __shfl_down(s, off);
    __syncthreads();
    if (lane == 0) sm.v.red[wave] = s;
    __syncthreads();
    s = sm.v.red[0] + sm.v.red[1] + sm.v.red[2] + sm.v.red[3]
      + sm.v.red[4] + sm.v.red[5] + sm.v.red[6] + sm.v.red[7];
    if (t < LP1) sm.v.pis[t] = e / s;
    __syncthreads();

    int lcnt   = (wave < 4) ? 25 : 24;
    int lstart = (wave < 4) ? wave * 25 : 100 + (wave - 4) * 24;
    int d0 = cy * 256 + lane * 4;
    const float* base = a.conv_feat + ((size_t)b * LCOUNT + lstart) * DIM + d0;
    f32x4 acc = {0.f, 0.f, 0.f, 0.f};
    #pragma unroll 5
    for (int i = 0; i < lcnt; ++i) {
      float4 x = *(const float4*)(base + (size_t)i * DIM);
      float p = sm.v.pis[lstart + i + 1];
      acc[0] += p * x.x; acc[1] += p * x.y;
      acc[2] += p * x.z; acc[3] += p * x.w;
    }
    int li = lane * 4;
    sm.v.partial[wave][li+0] = acc[0]; sm.v.partial[wave][li+1] = acc[1];
    sm.v.partial[wave][li+2] = acc[2]; sm.v.partial[wave][li+3] = acc[3];
    __syncthreads();
    if (t < 256) {
      float vsum = sm.v.partial[0][t] + sm.v.partial[1][t] + sm.v.partial[2][t]
                 + sm.v.partial[3][t] + sm.v.partial[4][t] + sm.v.partial[5][t]
                 + sm.v.partial[6][t] + sm.v.partial[7][t];
      int d = cy * 256 + t;
      vsum += sm.v.pis[0] * bf2f(a.fr_bf[b * DIM + d]);
      vsum += a.ho_f[b * DIM + d];
      a.attout[b * DIM + d] = (uint16_t)f2bf(vsum);
    }
  }
  grid.sync();

  // phase 2: h = tanh(attout@W_h^T + b_h) -> out. 512 tiles.
  for (int j = bid; j < 512; j += nb) {
    int m0 = (j & 7) * 16, n0 = (j >> 3) * 16;
    gemm_tile512<0,1>(a.attout, a.W_h, a.b_h, nullptr, a.out, 2, m0, n0, sm.glds);
  }
}

// ==== scores_k: unchanged R12 structure (6304 blocks, high TLP) ==============
__global__ __launch_bounds__(256) void scores_k(
    const float* __restrict__ cfe, const float* __restrict__ fre,
    const float* __restrict__ hoe, const float* __restrict__ Wa,
    const float* __restrict__ ba, float* __restrict__ scores)
{
  int row  = blockIdx.x * 4 + (threadIdx.x >> 6);
  int lane = threadIdx.x & 63;
  if (row >= BATCH * LP1) return;
  int b = row / LP1;
  int l = row - b * LP1;
  const float* xrow = (l == 0)
      ? (fre + (size_t)b * DIM)
      : (cfe + ((size_t)b * LCOUNT + (l - 1)) * DIM);
  const float* hrow = hoe + (size_t)b * DIM;
  float sum = 0.f;
  #pragma unroll
  for (int q = 0; q < 4; ++q) {
    int d = q * 256 + lane * 4;          // contiguous 1KB per wave-load
    float4 x = *(const float4*)(xrow + d);
    float4 h = *(const float4*)(hrow + d);
    float4 w = *(const float4*)(Wa + d);
    sum += tanh_fast(x.x + h.x) * w.x;
    sum += tanh_fast(x.y + h.y) * w.y;
    sum += tanh_fast(x.z + h.z) * w.z;
    sum += tanh_fast(x.w + h.w) * w.w;
  }
  #pragma unroll
  for (int off = 32; off > 0; off >>= 1) sum += __shfl_down(sum, off);
  if (lane == 0) scores[row] = sum + ba[0];
}

// ==== Fallback standalone kernels (R12-measured path) ========================
struct GemmArgs {
  const void* A; const void* W; const float* bias;
  uint16_t* out_bf; float* out_f; int act;
};

template<int AF32, int WF32>
__global__ __launch_bounds__(512) void gemm_k(GemmArgs g0, GemmArgs g1) {
  GemmArgs g = (blockIdx.z == 0) ? g0 : g1;
  __shared__ float lds[8][256];
  gemm_tile512<AF32, WF32>(g.A, g.W, g.bias, g.out_bf, g.out_f, g.act,
                           blockIdx.x * 16, blockIdx.y * 16, lds);
}

__global__ __launch_bounds__(512) void visatt_k(
    const float* __restrict__ cf, const uint16_t* __restrict__ frb,
    const float* __restrict__ hof, const float* __restrict__ scores,
    uint16_t* __restrict__ attout)
{
  int b = blockIdx.x, t = threadIdx.x;
  int lane = t & 63, wave = t >> 6;
  __shared__ float pis[LP1];
  __shared__ float red[8];
  __shared__ float partial[8][256];

  float v = (t < LP1) ? scores[b * LP1 + t] : -1e30f;
  float m = v;
  #pragma unroll
  for (int off = 32; off > 0; off >>= 1) m = fmaxf(m, __shfl_down(m, off));
  if (lane == 0) red[wave] = m;
  __syncthreads();
  m = fmaxf(fmaxf(fmaxf(red[0], red[1]), fmaxf(red[2], red[3])),
            fmaxf(fmaxf(red[4], red[5]), fmaxf(red[6], red[7])));
  float e = (t < LP1) ? __expf(v - m) : 0.f;
  float s = e;
  #pragma unroll
  for (int off = 32; off > 0; off >>= 1) s += __shfl_down(s, off);
  __syncthreads();
  if (lane == 0) red[wave] = s;
  __syncthreads();
  s = red[0] + red[1] + red[2] + red[3] + red[4] + red[5] + red[6] + red[7];
  if (t < LP1) pis[t] = e / s;
  __syncthreads();

  int lcnt   = (wave < 4) ? 25 : 24;
  int lstart = (wave < 4) ? wave * 25 : 100 + (wave - 4) * 24;
  int d0 = blockIdx.y * 256 + lane * 4;
  const float* base = cf + ((size_t)b * LCOUNT + lstart) * DIM + d0;
  f32x4 acc = {0.f, 0.f, 0.f, 0.f};
  #pragma unroll 5
  for (int i = 0; i < lcnt; ++i) {
    float4 x = *(const float4*)(base + (size_t)i * DIM);
    float p = pis[lstart + i + 1];
    acc[0] += p * x.x; acc[1] += p * x.y;
    acc[2] += p * x.z; acc[3] += p * x.w;
  }
  int li = lane * 4;
  partial[wave][li+0] = acc[0]; partial[wave][li+1] = acc[1];
  partial[wave][li+2] = acc[2]; partial[wave][li+3] = acc[3];
  __syncthreads();
  if (t < 256) {
    float vsum = partial[0][t] + partial[1][t] + partial[2][t] + partial[3][t]
               + partial[4][t] + partial[5][t] + partial[6][t] + partial[7][t];
    int d = blockIdx.y * 256 + t;
    vsum += pis[0] * bf2f(frb[b * DIM + d]);
    vsum += hof[b * DIM + d];
    attout[b * DIM + d] = (uint16_t)f2bf(vsum);
  }
}

// ---------------- launch -----------------------------------------------------
extern "C" void kernel_launch(void* const* d_in, const int* in_sizes, int n_in,
                              void* d_out, int out_size, void* d_ws, size_t ws_size,
                              hipStream_t stream) {
  FusedArgs fa;
  fa.h_out       = (const float*)d_in[0];
  fa.fake_region = (const float*)d_in[1];
  fa.conv_feat   = (const float*)d_in[2];
  fa.conv_feat_e = (const float*)d_in[3];
  fa.W_fr  = (const float*)d_in[4];
  fa.b_fr  = (const float*)d_in[5];
  fa.W_fre = (const float*)d_in[6];
  fa.b_fre = (const float*)d_in[7];
  fa.W_ho  = (const float*)d_in[8];
  fa.b_ho  = (const float*)d_in[9];
  fa.W_hoe = (const float*)d_in[10];
  fa.b_hoe = (const float*)d_in[11];
  fa.W_a   = (const float*)d_in[12];
  fa.b_a   = (const float*)d_in[13];
  fa.W_h   = (const float*)d_in[14];
  fa.b_h   = (const float*)d_in[15];

  char* ws = (char*)d_ws;
  fa.fr_bf  = (uint16_t*)(ws + 0);        // 256 KB [128,1024] bf16
  fa.ho_bf  = (uint16_t*)(ws + 262144);   // 256 KB
  fa.attout = (uint16_t*)(ws + 524288);   // 256 KB
  fa.ho_f   = (float*)   (ws + 786432);   // 512 KB [128,1024] fp32
  fa.fre_f  = (float*)   (ws + 1310720);  // 512 KB
  fa.hoe_f  = (float*)   (ws + 1835008);  // 512 KB
  fa.scores = (float*)   (ws + 2359296);  // ~100 KB [128,197]
  fa.out    = (float*)d_out;

  void* kargs[] = { (void*)&fa };

  // ---- K12: steps 1+2 (coop, 2 phases) ----
  int maxb12 = 0;
  hipOccupancyMaxActiveBlocksPerMultiprocessor(&maxb12, (const void*)k12, 512, 0);
  hipError_t e1 = hipErrorUnknown;
  if (maxb12 >= 1) {
    int g12 = maxb12 * 256; if (g12 > 1024) g12 = 1024;
    e1 = hipLaunchCooperativeKernel((const void*)k12, dim3(g12), dim3(512),
                                    kargs, 0, stream);
  }
  if (e1 != hipSuccess) {               // fallback: R12-measured 2 dispatches
    GemmArgs ga{fa.fake_region, fa.W_fr, fa.b_fr, fa.fr_bf, nullptr, 1};
    GemmArgs gb{fa.h_out,       fa.W_ho, fa.b_ho, fa.ho_bf, fa.ho_f,  2};
    gemm_k<1,1><<<dim3(8, 64, 2), dim3(512), 0, stream>>>(ga, gb);
    GemmArgs gc{fa.fr_bf, fa.W_fre, fa.b_fre, nullptr, fa.fre_f, 0};
    GemmArgs gd{fa.ho_bf, fa.W_hoe, fa.b_hoe, nullptr, fa.hoe_f, 0};
    gemm_k<0,1><<<dim3(8, 64, 2), dim3(512), 0, stream>>>(gc, gd);
  }

  // ---- scores (unchanged high-TLP structure) ----
  scores_k<<<dim3((BATCH * LP1) / 4), dim3(256), 0, stream>>>(
      fa.conv_feat_e, fa.fre_f, fa.hoe_f, fa.W_a, fa.b_a, fa.scores);

  // ---- K45: visatt + step-5 GEMM (coop, 2 phases) ----
  int maxb45 = 0;
  hipOccupancyMaxActiveBlocksPerMultiprocessor(&maxb45, (const void*)k45, 512, 0);
  hipError_t e2 = hipErrorUnknown;
  if (maxb45 >= 1) {
    int g45 = maxb45 * 256; if (g45 > 512) g45 = 512;
    e2 = hipLaunchCooperativeKernel((const void*)k45, dim3(g45), dim3(512),
                                    kargs, 0, stream);
  }
  if (e2 != hipSuccess) {               // fallback: R12-measured 2 dispatches
    visatt_k<<<dim3(BATCH, 4), dim3(512), 0, stream>>>(
        fa.conv_feat, fa.fr_bf, fa.ho_f, fa.scores, fa.attout);
    GemmArgs ge{fa.attout, fa.W_h, fa.b_h, nullptr, fa.out, 2};
    gemm_k<0,1><<<dim3(8, 64, 1), dim3(512), 0, stream>>>(ge, ge);
  }
}

// Round 15
// 291.703 us; speedup vs baseline: 1.4424x; 1.4424x over previous
//
#include <hip/hip_runtime.h>
#include <stdint.h>

#define BATCH 128
#define LCOUNT 196
#define LP1 197
#define DIM 1024

typedef __bf16 bf16x8 __attribute__((ext_vector_type(8)));
typedef float f32x4 __attribute__((ext_vector_type(4)));

__device__ inline float bf2f(uint16_t h){ union{uint32_t i; float f;} x; x.i = ((uint32_t)h) << 16; return x.f; }
__device__ inline uint32_t f2bf(float f){
  union{float f; uint32_t u;} x; x.f = f;
  uint32_t r = x.u + 0x7fffu + ((x.u >> 16) & 1u);
  return r >> 16;
}
__device__ inline float tanh_fast(float x){
  float e = __expf(2.0f * x);
  return 1.0f - 2.0f / (e + 1.0f);
}

// load 8 contiguous fp32 and convert to bf16x8 (RNE, same as f2bf)
__device__ inline bf16x8 cvt8(const float* p){
  float4 a = *(const float4*)p;
  float4 b = *(const float4*)(p + 4);
  bf16x8 r;
  r[0] = (__bf16)a.x; r[1] = (__bf16)a.y; r[2] = (__bf16)a.z; r[3] = (__bf16)a.w;
  r[4] = (__bf16)b.x; r[5] = (__bf16)b.y; r[6] = (__bf16)b.z; r[7] = (__bf16)b.w;
  return r;
}

// ---------------- GEMM: C[m,n] = act(sum_k A[m,k]*W[n,k] + bias[n]) ----------
// M=128, N=1024, K=1024. A/W fp32 (in-register cvt) or bf16.
// R14 fix: grid (64, 8, z) with n-tile on blockIdx.x. HIP linear dispatch id
// i = x + 64*y, so i%8 = n_tile%8: the 8 m-blocks sharing one W panel land on
// ONE XCD -> W fetched once per device, not 8x (R14 k12 profile: FETCH 66.6MB
// vs ~19MB unique = 8x W duplication across XCD L2s).
// 512-thread blocks, 8-way split-K; block = one 16x16 output tile.
struct GemmArgs {
  const void* A;         // [128,1024] fp32 or bf16
  const void* W;         // [1024,1024] fp32 or bf16, row-major [N,K]
  const float* bias;     // [1024] fp32
  uint16_t* out_bf;      // bf16 out or null
  float*    out_f;       // fp32 out or null
  int act;               // 0 none, 1 relu, 2 tanh
};

template<int AF32, int WF32>
__global__ __launch_bounds__(512) void gemm_k(GemmArgs g0, GemmArgs g1) {
  GemmArgs g = (blockIdx.z == 0) ? g0 : g1;
  const int K = DIM, N = DIM;
  int wave = threadIdx.x >> 6;          // 0..7, K-slice index
  int lane = threadIdx.x & 63;
  int r    = lane & 15;
  int quad = lane >> 4;
  int m0 = blockIdx.y * 16;             // 8 m-tiles   (slow dim)
  int n0 = blockIdx.x * 16;             // 64 n-tiles  (fast dim -> XCD id)
  size_t aoff = (size_t)(m0 + r) * K + wave * 128 + quad * 8;
  size_t woff = (size_t)(n0 + r) * K + wave * 128 + quad * 8;
  const float*    Af = (const float*)g.A    + aoff;
  const uint16_t* Ab = (const uint16_t*)g.A + aoff;
  const float*    Wf = (const float*)g.W    + woff;
  const uint16_t* Wb = (const uint16_t*)g.W + woff;
  f32x4 acc = {0.f, 0.f, 0.f, 0.f};
  #pragma unroll
  for (int k = 0; k < 128; k += 32) {
    bf16x8 a = AF32 ? cvt8(Af + k) : *(const bf16x8*)(Ab + k);
    bf16x8 b = WF32 ? cvt8(Wf + k) : *(const bf16x8*)(Wb + k);
    acc = __builtin_amdgcn_mfma_f32_16x16x32_bf16(a, b, acc, 0, 0, 0);
  }
  // C/D layout: col = lane&15, row = quad*4 + i   [verified m89/m91, R4 pass]
  __shared__ float lds[8][256];
  int li = lane * 4;
  lds[wave][li+0] = acc[0]; lds[wave][li+1] = acc[1];
  lds[wave][li+2] = acc[2]; lds[wave][li+3] = acc[3];
  __syncthreads();
  int t = threadIdx.x;
  if (t < 256) {
    float v = lds[0][t] + lds[1][t] + lds[2][t] + lds[3][t]
            + lds[4][t] + lds[5][t] + lds[6][t] + lds[7][t];
    int col = (t >> 2) & 15;             // lane&15 of producer
    int row = (t >> 6) * 4 + (t & 3);    // quad*4 + i of producer
    v += g.bias[n0 + col];
    if (g.act == 1) v = fmaxf(v, 0.f);
    else if (g.act == 2) v = tanh_fast(v);
    size_t idx = (size_t)(m0 + row) * N + (n0 + col);
    if (g.out_bf) g.out_bf[idx] = (uint16_t)f2bf(v);
    if (g.out_f)  g.out_f[idx]  = v;
  }
}

// ---------------- scores[b,l] = dot(tanh(embed_row + hoe[b]), Wa) + ba -------
// One wave per (b,l) row; 4 rows per 256-thread block. 6304 blocks (high TLP,
// measured structure, untouched).
__global__ __launch_bounds__(256) void scores_k(
    const float* __restrict__ cfe,   // [B,196,1024] fp32 (raw input)
    const float* __restrict__ fre,   // [B,1024] fp32 (ws)
    const float* __restrict__ hoe,   // [B,1024] fp32 (ws)
    const float* __restrict__ Wa,    // [1024] fp32 (raw input)
    const float* __restrict__ ba,    // [1] fp32 (raw input)
    float* __restrict__ scores)      // [B,197]
{
  int row  = blockIdx.x * 4 + (threadIdx.x >> 6);
  int lane = threadIdx.x & 63;
  if (row >= BATCH * LP1) return;
  int b = row / LP1;
  int l = row - b * LP1;

  const float* xrow = (l == 0)
      ? (fre + (size_t)b * DIM)
      : (cfe + ((size_t)b * LCOUNT + (l - 1)) * DIM);
  const float* hrow = hoe + (size_t)b * DIM;
  float sum = 0.f;
  #pragma unroll
  for (int q = 0; q < 4; ++q) {
    int d = q * 256 + lane * 4;          // contiguous 1KB per wave-load
    float4 x = *(const float4*)(xrow + d);
    float4 h = *(const float4*)(hrow + d);
    float4 w = *(const float4*)(Wa + d);
    sum += tanh_fast(x.x + h.x) * w.x;
    sum += tanh_fast(x.y + h.y) * w.y;
    sum += tanh_fast(x.z + h.z) * w.z;
    sum += tanh_fast(x.w + h.w) * w.w;
  }
  #pragma unroll
  for (int off = 32; off > 0; off >>= 1) sum += __shfl_down(sum, off);
  if (lane == 0) scores[row] = sum + ba[0];
}

// ---------------- softmax(scores[b]) fused with visAtt + ho -> attout --------
// grid (128, 4): block handles batch b, 256-dim chunk. 512-thread blocks,
// 8 waves split the 196 conv slots (25/24 each). Measured structure (R12).
__global__ __launch_bounds__(512) void visatt_k(
    const float*    __restrict__ cf,      // [B,196,1024] fp32 (raw input)
    const uint16_t* __restrict__ frb,     // [B,1024] bf16 (ws)
    const float*    __restrict__ hof,     // [B,1024] fp32 (ws)
    const float*    __restrict__ scores,  // [B,197] (ws)
    uint16_t* __restrict__ attout)        // [B,1024] bf16
{
  int b = blockIdx.x, t = threadIdx.x;
  int lane = t & 63, wave = t >> 6;      // 8 waves
  __shared__ float pis[LP1];
  __shared__ float red[8];
  __shared__ float partial[8][256];

  // --- softmax over 197 scores (threads >=197 contribute identity) ---
  float v = (t < LP1) ? scores[b * LP1 + t] : -1e30f;
  float m = v;
  #pragma unroll
  for (int off = 32; off > 0; off >>= 1) m = fmaxf(m, __shfl_down(m, off));
  if (lane == 0) red[wave] = m;
  __syncthreads();
  m = fmaxf(fmaxf(fmaxf(red[0], red[1]), fmaxf(red[2], red[3])),
            fmaxf(fmaxf(red[4], red[5]), fmaxf(red[6], red[7])));
  float e = (t < LP1) ? __expf(v - m) : 0.f;
  float s = e;
  #pragma unroll
  for (int off = 32; off > 0; off >>= 1) s += __shfl_down(s, off);
  __syncthreads();
  if (lane == 0) red[wave] = s;
  __syncthreads();
  s = red[0] + red[1] + red[2] + red[3] + red[4] + red[5] + red[6] + red[7];
  if (t < LP1) pis[t] = e / s;
  __syncthreads();

  // --- weighted sum over l: wave w handles lcnt l's starting at lstart ---
  int lcnt   = (wave < 4) ? 25 : 24;
  int lstart = (wave < 4) ? wave * 25 : 100 + (wave - 4) * 24;
  int d0 = blockIdx.y * 256 + lane * 4;
  const float* base = cf + ((size_t)b * LCOUNT + lstart) * DIM + d0;
  f32x4 acc = {0.f, 0.f, 0.f, 0.f};
  #pragma unroll 5
  for (int i = 0; i < lcnt; ++i) {
    float4 x = *(const float4*)(base + (size_t)i * DIM);
    float p = pis[lstart + i + 1];       // LDS broadcast (conflict-free)
    acc[0] += p * x.x; acc[1] += p * x.y;
    acc[2] += p * x.z; acc[3] += p * x.w;
  }
  int li = lane * 4;
  partial[wave][li+0] = acc[0]; partial[wave][li+1] = acc[1];
  partial[wave][li+2] = acc[2]; partial[wave][li+3] = acc[3];
  __syncthreads();

  // --- cross-wave reduce + fr slot + ho residual, store bf16 ---
  if (t < 256) {
    float vsum = partial[0][t] + partial[1][t] + partial[2][t] + partial[3][t]
               + partial[4][t] + partial[5][t] + partial[6][t] + partial[7][t];
    int d = blockIdx.y * 256 + t;
    vsum += pis[0] * bf2f(frb[b * DIM + d]);
    vsum += hof[b * DIM + d];
    attout[b * DIM + d] = (uint16_t)f2bf(vsum);
  }
}

// ---------------- launch -----------------------------------------------------
extern "C" void kernel_launch(void* const* d_in, const int* in_sizes, int n_in,
                              void* d_out, int out_size, void* d_ws, size_t ws_size,
                              hipStream_t stream) {
  const float* h_out       = (const float*)d_in[0];
  const float* fake_region = (const float*)d_in[1];
  const float* conv_feat   = (const float*)d_in[2];
  const float* conv_feat_e = (const float*)d_in[3];
  const float* W_fr  = (const float*)d_in[4];
  const float* b_fr  = (const float*)d_in[5];
  const float* W_fre = (const float*)d_in[6];
  const float* b_fre = (const float*)d_in[7];
  const float* W_ho  = (const float*)d_in[8];
  const float* b_ho  = (const float*)d_in[9];
  const float* W_hoe = (const float*)d_in[10];
  const float* b_hoe = (const float*)d_in[11];
  const float* W_a   = (const float*)d_in[12];
  const float* b_a   = (const float*)d_in[13];
  const float* W_h   = (const float*)d_in[14];
  const float* b_h   = (const float*)d_in[15];

  char* ws = (char*)d_ws;
  uint16_t* fr_bf   = (uint16_t*)(ws + 0);        // 256 KB [128,1024] bf16
  uint16_t* ho_bf   = (uint16_t*)(ws + 262144);   // 256 KB
  uint16_t* attout  = (uint16_t*)(ws + 524288);   // 256 KB
  float*    ho_f    = (float*)   (ws + 786432);   // 512 KB [128,1024] fp32
  float*    fre_f   = (float*)   (ws + 1310720);  // 512 KB
  float*    hoe_f   = (float*)   (ws + 1835008);  // 512 KB
  float*    scores  = (float*)   (ws + 2359296);  // ~100 KB [128,197]

  // Grid (64, 8, z): n-tile fastest -> all m-blocks for one W panel share an
  // XCD (see gemm_k comment). No cooperative launches: R9/R14 measured coop
  // kernels capped at ~580 GB/s effective (2.5-3x slower than dispatches).

  // 1: fr = relu(fake_region@W_fr^T+b), ho = tanh(h_out@W_ho^T+b)
  GemmArgs ga{fake_region, W_fr, b_fr, fr_bf, nullptr, 1};
  GemmArgs gb{h_out,       W_ho, b_ho, ho_bf, ho_f,    2};
  gemm_k<1,1><<<dim3(64, 8, 2), dim3(512), 0, stream>>>(ga, gb);

  // 2: fr_e = fr@W_fre^T+b, ho_e = ho@W_hoe^T+b  (fp32 outputs)
  GemmArgs gc{fr_bf, W_fre, b_fre, nullptr, fre_f, 0};
  GemmArgs gd{ho_bf, W_hoe, b_hoe, nullptr, hoe_f, 0};
  gemm_k<0,1><<<dim3(64, 8, 2), dim3(512), 0, stream>>>(gc, gd);

  // 3: attention scores over L+1 = 197 slots
  scores_k<<<dim3((BATCH * LP1) / 4), dim3(256), 0, stream>>>(
      conv_feat_e, fre_f, hoe_f, W_a, b_a, scores);

  // 4: softmax + visAtt + ho -> attout (bf16)
  visatt_k<<<dim3(BATCH, 4), dim3(512), 0, stream>>>(
      conv_feat, fr_bf, ho_f, scores, attout);

  // 5: h = tanh(attout@W_h^T + b_h) -> d_out (fp32)
  GemmArgs ge{attout, W_h, b_h, nullptr, (float*)d_out, 2};
  gemm_k<0,1><<<dim3(64, 8, 1), dim3(512), 0, stream>>>(ge, ge);
}